// Round 1
// 93.925 us; speedup vs baseline: 1.0034x; 1.0034x over previous
//
#include <hip/hip_runtime.h>
#include <hip/hip_bf16.h>

// LowRankBilinearPooling: out[b,o] = (sum_i relu(x1 W1))_h * (sum_j relu(x2 W2))_h @ Wp + bp*196^2
// B=16, N=196, C=768, H=512, O=128. fp32 in/out; bf16 MFMA inside.
// R1: w_tile prepass folded into gemm staging (W converted fp32->bf16 in-register
//     during the same reg->LDS stage as A). One fewer serialized launch.

#define NB 16
#define NROW 196
#define KC_ 768
#define HH 512
#define OO 128

using short4v = __attribute__((ext_vector_type(4))) short;
using short8 = __attribute__((ext_vector_type(8))) short;
using f32x16 = __attribute__((ext_vector_type(16))) float;

__device__ __forceinline__ short2 pk2bf(float a, float b) {
    // lowers to v_cvt_pk_bf16_f32 on gfx950 (1 op / 2 elems)
    __hip_bfloat162 h = __float22bfloat162_rn(make_float2(a, b));
    union { __hip_bfloat162 h; short2 s; } u; u.h = h;
    return u.s;
}

// Kernel 1: fused GEMM + relu + row-sum, with inline W conversion.
// Grid: 256 blocks = 2(branch) x 16(b) x 4(ht) x 2(mh). Block: 512 thr = 8 waves
// = (mp 0..3: 32-row tile) x (sp 0..1: 64-col strip). K chunked by 64,
// double-buffered LDS, one barrier per chunk. LDS plane stride 129 units (pad).
// B staging: thread t owns units (p=t>>7, col=t&127) and (p+4, col); each unit
// = 8 k-consecutive W elements, loaded as 8 stride-HH dwords (coalesced across
// lanes: 64 consecutive floats per instruction), packed to bf16 short8, stored
// with ds_write_b128 at the exact addresses the MFMA fragment reads expect.
__global__ __launch_bounds__(512, 1)
void gemm_relu_rowsum(const float* __restrict__ x1, const float* __restrict__ x2,
                      const float* __restrict__ W1, const float* __restrict__ W2,
                      float* __restrict__ sbuf) {
    __shared__ unsigned short Alds[2][8 * 129 * 8];
    __shared__ unsigned short Blds[2][8 * 129 * 8];
    __shared__ float psum[16 * 32];

    const int bid = blockIdx.x;
    const int p  = bid & 31;           // (branch,b): tiles of same x[b] share an XCD
    const int tt = bid >> 5;
    const int branch = p >> 4;
    const int b      = p & 15;
    const int ht = tt >> 1;
    const int mh = tt & 1;

    const float* __restrict__ x  = branch ? x2 : x1;
    const float* __restrict__ Wf = branch ? W2 : W1;

    const int t   = threadIdx.x;
    const int l16 = t & 15;            // A: 16B slot within a row's 256B chunk-span
    const int rg  = t >> 4;            // A: row group 0..31 (row = rg + 32*r)
    const float* xbase = x + (b * NROW + mh * 128) * KC_ + l16 * 4;

    const int bp0 = t >> 7;            // B unit plane 0..3 (owns p=bp0 and p=bp0+4)
    const int bc0 = t & 127;           // B unit column
    // W element for unit (p,col), lane j: W[(kc*64 + p*8 + j)*HH + ht*128 + col]
    const float* wbase = Wf + (bp0 * 8) * HH + ht * 128 + bc0;

    float4 av[4];
    float bf0[8], bf1[8];

    auto load_stage = [&](int kc) {
#pragma unroll
        for (int r = 0; r < 4; ++r) {
            const int row = rg + 32 * r;
            if (mh * 128 + row < NROW)
                av[r] = *(const float4*)(xbase + row * KC_ + kc * 64);
            else
                av[r] = make_float4(0.f, 0.f, 0.f, 0.f);
        }
        const float* wc = wbase + kc * 64 * HH;
#pragma unroll
        for (int j = 0; j < 8; ++j) bf0[j] = wc[j * HH];            // unit (bp0,  col)
#pragma unroll
        for (int j = 0; j < 8; ++j) bf1[j] = wc[16384 + j * HH];    // unit (bp0+4,col): +4*8*HH
    };

    auto write_stage = [&](int buf) {
#pragma unroll
        for (int r = 0; r < 4; ++r) {
            short4v sv; short2 s;
            s = pk2bf(av[r].x, av[r].y); sv[0] = s.x; sv[1] = s.y;
            s = pk2bf(av[r].z, av[r].w); sv[2] = s.x; sv[3] = s.y;
            const int row = rg + 32 * r;
            *(short4v*)&Alds[buf][((l16 >> 1) * 129 + row) * 8 + (l16 & 1) * 4] = sv;
        }
        short8 v0, v1; short2 s;
#pragma unroll
        for (int j = 0; j < 4; ++j) {
            s = pk2bf(bf0[2 * j], bf0[2 * j + 1]); v0[2 * j] = s.x; v0[2 * j + 1] = s.y;
            s = pk2bf(bf1[2 * j], bf1[2 * j + 1]); v1[2 * j] = s.x; v1[2 * j + 1] = s.y;
        }
        *(short8*)&Blds[buf][(bp0 * 129 + bc0) * 8] = v0;           // lane-contiguous: conflict-free
        *(short8*)&Blds[buf][((bp0 + 4) * 129 + bc0) * 8] = v1;
    };

    const int w  = t >> 6;
    const int l  = t & 63;
    const int m  = l & 31;
    const int q  = l >> 5;
    const int sp = w & 1;              // 64-col strip
    const int mp = w >> 1;             // 32-row tile
    const int aoff = (mp * 32 + m) * 8;
    const int boff = (sp * 64 + m) * 8;

    f32x16 acc0 = {}, acc1 = {};

    load_stage(0);
    write_stage(0);
    load_stage(1);
    __syncthreads();

#pragma unroll 1
    for (int kc = 0; kc < 12; ++kc) {
        const int pb = kc & 1;
#pragma unroll
        for (int ks = 0; ks < 4; ++ks) {
            const int base = (ks * 2 + q) * 129 * 8;
            short8 af = *(const short8*)&Alds[pb][base + aoff];
            short8 b0 = *(const short8*)&Blds[pb][base + boff];
            short8 b1 = *(const short8*)&Blds[pb][base + boff + 256];
            acc0 = __builtin_amdgcn_mfma_f32_32x32x16_bf16(af, b0, acc0, 0, 0, 0);
            acc1 = __builtin_amdgcn_mfma_f32_32x32x16_bf16(af, b1, acc1, 0, 0, 0);
        }
        if (kc < 11) write_stage(1 - pb);   // chunk kc+1 -> other buffer
        if (kc < 10) load_stage(kc + 2);    // prefetch chunk kc+2
        __syncthreads();                    // one barrier per chunk
    }

    // relu + sum over rows. C layout: col = lane&31 (m101); lanes l and l^32's
    // 16 regs together cover all 32 rows, order irrelevant for a sum.
    float cs0 = 0.f, cs1 = 0.f;
#pragma unroll
    for (int r = 0; r < 16; ++r) {
        cs0 += fmaxf(acc0[r], 0.f);
        cs1 += fmaxf(acc1[r], 0.f);
    }
    cs0 += __shfl_xor(cs0, 32);
    cs1 += __shfl_xor(cs1, 32);
    if (l < 32) {
        psum[((sp * 2 + 0) * 4 + mp) * 32 + l] = cs0;  // col tile 2sp
        psum[((sp * 2 + 1) * 4 + mp) * 32 + l] = cs1;  // col tile 2sp+1
    }
    __syncthreads();
    if (t < 128) {
        const int ct = t >> 5;
        const int cl = t & 31;
        float v = 0.f;
#pragma unroll
        for (int mp2 = 0; mp2 < 4; ++mp2)
            v += psum[(ct * 4 + mp2) * 32 + cl];
        sbuf[((branch * 2 + mh) * NB + b) * HH + ht * 128 + t] = v;
    }
}

// Kernel 2: out[b,o] = sum_h (s1[b,h]*s2[b,h]) * Wp[h,o] + bp[o]*196^2
__global__ __launch_bounds__(512)
void proj_kernel(const float* __restrict__ sbuf, const float* __restrict__ Wp,
                 const float* __restrict__ bp, float* __restrict__ out) {
    __shared__ float spl[HH];
    __shared__ float red[4][OO];
    const int b = blockIdx.x, t = threadIdx.x;
    {
        const float s1 = sbuf[(0 * NB + b) * HH + t] + sbuf[(1 * NB + b) * HH + t];
        const float s2 = sbuf[(2 * NB + b) * HH + t] + sbuf[(3 * NB + b) * HH + t];
        spl[t] = s1 * s2;
    }
    __syncthreads();
    const int to = t & 127, hq = t >> 7;
    float acc = 0.f;
#pragma unroll 8
    for (int h = hq * 128; h < hq * 128 + 128; ++h)
        acc += spl[h] * Wp[h * OO + to];
    red[hq][to] = acc;
    __syncthreads();
    if (t < OO)
        out[b * OO + t] = red[0][t] + red[1][t] + red[2][t] + red[3][t]
                        + bp[t] * 38416.0f;   // 196*196
}

extern "C" void kernel_launch(void* const* d_in, const int* in_sizes, int n_in,
                              void* d_out, int out_size, void* d_ws, size_t ws_size,
                              hipStream_t stream) {
    const float* x1 = (const float*)d_in[0];
    const float* x2 = (const float*)d_in[1];
    const float* W1 = (const float*)d_in[2];
    const float* W2 = (const float*)d_in[3];
    const float* Wp = (const float*)d_in[4];
    const float* bp = (const float*)d_in[5];
    float* sbuf = (float*)d_ws;                                  // 128 KB

    gemm_relu_rowsum<<<256, 512, 0, stream>>>(x1, x2, W1, W2, sbuf);
    proj_kernel<<<NB, 512, 0, stream>>>(sbuf, Wp, bp, (float*)d_out);
}